// Round 11
// baseline (171.086 us; speedup 1.0000x reference)
//
#include <hip/hip_runtime.h>
#include <hip/hip_bf16.h>
#include <stdint.h>

// BevFormer block: temporal MHA + LN, spatial cross-MHA(+proj) + LN, FFN + LN.
// I/O f32; internal bf16 MFMA + f32 accum. Flash attention (KVSPLIT=3,
// fixed-max exp2 softmax, 32x32x16 MFMA, in-register P via permlane32_swap,
// XCD-pinned swizzle, 2 kv-tiles x 2 q-tiles/iter), mfma32 GEMM bodies,
// fused GEMM+LN tails, merge2 fused into s_wo GEMM. Round 11: BARRIER-FREE
// attention -- V fragments loaded directly from global (per-lane scalar bf16,
// coalesced 64B/half-wave, L2-resident) in the exact mfma B-operand layout
// (k = 8*hi + e), eliminating LDS staging, ds_read, and all __syncthreads.
// Waves run fully independent; softmax chains sequentialized for registers.

typedef __bf16 bf16_t;
typedef __bf16 bf16x8 __attribute__((ext_vector_type(8)));
typedef __bf16 bf16x4 __attribute__((ext_vector_type(4)));
typedef float  f32x4  __attribute__((ext_vector_type(4)));
typedef float  f32x16 __attribute__((ext_vector_type(16)));
typedef uint32_t u32;
typedef uint32_t u32x4 __attribute__((ext_vector_type(4)));

#define NB   2
#define SEQ  2500
#define EMB  256
#define NH   8
#define HD   32
#define MTOT (NB*SEQ)
#define KVSPLIT 3
#define SPLITLEN 834       // splits: [0,834) [834,1668) [1668,2500)
#define NPAIR 14           // 14 pairs = 28 tiles = 896 kv slots (tail masked)

static __device__ __forceinline__ f32x4 mfma16(bf16x8 a, bf16x8 b, f32x4 c) {
  return __builtin_amdgcn_mfma_f32_16x16x32_bf16(a, b, c, 0, 0, 0);
}
static __device__ __forceinline__ f32x16 mfma32(bf16x8 a, bf16x8 b, f32x16 c) {
  return __builtin_amdgcn_mfma_f32_32x32x16_bf16(a, b, c, 0, 0, 0);
}
static __device__ __forceinline__ u32 pack2(float a, float b) {
  union { __bf16 h; unsigned short s; } x, y;
  x.h = (__bf16)a; y.h = (__bf16)b;
  return (u32)x.s | ((u32)y.s << 16);
}

// ---------------- prep: weight transpose->bf16 + activation cvt ----------------
__global__ __launch_bounds__(256) void prep_kernel(
    const float* s0, const float* s1, const float* s2, const float* s3,
    const float* s4, const float* s5, const float* s6, const float* s7,
    const float* s8, bf16_t* wt,
    const float* aq, const float* ap, const float* ai,
    bf16_t* dq, bf16_t* dp, bf16_t* di)
{
  int b = blockIdx.x;
  if (b < 176) {
    const float* src; int R, C, tl; size_t doff;
    if (b < 112) {
      int mi = b >> 4; tl = b & 15; R = 256; C = 256; doff = (size_t)mi * 65536;
      switch (mi) {
        case 0: src = s0; break; case 1: src = s1; break; case 2: src = s2; break;
        case 3: src = s3; break; case 4: src = s4; break; case 5: src = s5; break;
        default: src = s6;
      }
    } else if (b < 144) { tl = b - 112; R = 256; C = 512; doff = 458752; src = s7; }
    else                { tl = b - 144; R = 512; C = 256; doff = 589824; src = s8; }
    const int tpr = C >> 6;
    const int tr = tl / tpr, tc = tl % tpr;
    bf16_t* dst = wt + doff;
    #pragma unroll
    for (int i = 0; i < 16; ++i) {
      int lin = i * 256 + threadIdx.x;
      int lr = lin >> 6, lc = lin & 63;
      int rr = tr * 64 + lr, cc = tc * 64 + lc;
      dst[(size_t)cc * R + rr] = (__bf16)src[(size_t)rr * C + cc];
    }
    return;
  }
  int idx = b - 176;
  int t = idx / 313, r = idx % 313;
  const float* src = (t == 0) ? aq : (t == 1) ? ap : ai;
  bf16_t* dst = (t == 0) ? dq : (t == 1) ? dp : di;
  #pragma unroll
  for (int k = 0; k < 4; ++k) {
    int i = r * 1024 + k * 256 + threadIdx.x;
    if (i < 320000) {
      float4 v = ((const float4*)src)[i];
      bf16x4 o;
      o[0] = (__bf16)v.x; o[1] = (__bf16)v.y; o[2] = (__bf16)v.z; o[3] = (__bf16)v.w;
      ((bf16x4*)dst)[i] = o;
    }
  }
}

// -------- mfma32 GEMM body: wave = 32 rows x 64 cols; block = 4 waves = 128 rows.
template<int K>
static __device__ __forceinline__ void gemm32_body(
    const bf16_t* __restrict__ A, const bf16_t* __restrict__ Wt,
    const float* __restrict__ bias, bf16_t* __restrict__ Cout,
    int M, int N, int relu, float cscale, int bx, int by)
{
  const int tid = threadIdx.x;
  const int lane = tid & 63, wid = tid >> 6;
  const int l31 = lane & 31, hi = lane >> 5;
  const int mbase = bx * 128 + wid * 32;
  const int nbase = by * 64;

  int arow = mbase + l31; if (arow > M - 1) arow = M - 1;
  const bf16_t* ap = A + (size_t)arow * K + hi * 8;
  const bf16_t* bp = Wt + (size_t)(nbase + l31) * K + hi * 8;

  f32x16 acc0 = {}, acc1 = {};
  #pragma unroll
  for (int kk = 0; kk < K; kk += 16) {
    bf16x8 a  = *(const bf16x8*)(ap + kk);
    bf16x8 b0 = *(const bf16x8*)(bp + kk);
    bf16x8 b1 = *(const bf16x8*)(bp + (size_t)32 * K + kk);
    acc0 = mfma32(a, b0, acc0);
    acc1 = mfma32(a, b1, acc1);
  }
  #pragma unroll
  for (int r = 0; r < 16; ++r) {
    const int row = mbase + (r & 3) + ((r >> 2) << 3) + hi * 4;
    if (row < M) {
      const int c0 = nbase + l31;
      const int c1 = nbase + 32 + l31;
      float v0 = acc0[r] * cscale + (bias ? bias[c0] : 0.f);
      float v1 = acc1[r] * cscale + (bias ? bias[c1] : 0.f);
      if (relu) { v0 = fmaxf(v0, 0.f); v1 = fmaxf(v1, 0.f); }
      Cout[(size_t)row * N + c0] = (bf16_t)v0;
      Cout[(size_t)row * N + c1] = (bf16_t)v1;
    }
  }
}

// x2 @ WTF1 (+bias, relu), N=512, K=256
__global__ __launch_bounds__(256) void gemm_relu_kernel(
    const bf16_t* __restrict__ A, const bf16_t* __restrict__ Wt,
    const float* __restrict__ bias, bf16_t* __restrict__ Cout,
    int M, int N)
{
  gemm32_body<256>(A, Wt, bias, Cout, M, N, 1, 1.f, blockIdx.x, blockIdx.y);
}

// five batched projections: temporal Q/K/V + spatial K/V (spatial K/V only
// depend on prep, so they ride the first launch). qsc applied to z==0.
__global__ __launch_bounds__(256) void proj5_kernel(
    const bf16_t* qbf, const bf16_t* pbf, const bf16_t* ibf,
    const bf16_t* WT,
    bf16_t* tq, bf16_t* tk, bf16_t* tv, bf16_t* sk, bf16_t* sv, float qsc)
{
  const int z = blockIdx.z;
  const bf16_t* A; const bf16_t* W; bf16_t* C; float cs = 1.f;
  switch (z) {
    case 0:  A = qbf; W = WT;          C = tq; cs = qsc; break;
    case 1:  A = pbf; W = WT + 65536;  C = tk; break;
    case 2:  A = pbf; W = WT + 131072; C = tv; break;
    case 3:  A = ibf; W = WT + 262144; C = sk; break;
    default: A = ibf; W = WT + 327680; C = sv; break;
  }
  gemm32_body<256>(A, W, nullptr, C, MTOT, 256, 0, cs, blockIdx.x, blockIdx.y);
}

// single scaled projection: spatial Q = x1 @ s_wq * qscS
__global__ __launch_bounds__(256) void projq_kernel(
    const bf16_t* __restrict__ A, const bf16_t* __restrict__ W,
    bf16_t* __restrict__ C, float sc)
{
  gemm32_body<256>(A, W, nullptr, C, MTOT, 256, 0, sc, blockIdx.x, blockIdx.y);
}

// -------- fused [merge partials] + GEMM(s_wo) + bias + residual + LN --------
__global__ __launch_bounds__(256) void gemm_ln_merge_kernel(
    const bf16_t* __restrict__ Op0, const bf16_t* __restrict__ Op1,
    const bf16_t* __restrict__ Op2, const float* __restrict__ Lp,
    const bf16_t* __restrict__ Wt, const float* __restrict__ bias,
    const bf16_t* __restrict__ resid, const float* __restrict__ gw,
    const float* __restrict__ bw, bf16_t* __restrict__ OutB, int M)
{
  __shared__ float red[16][4][2];
  const int tid = threadIdx.x;
  const int lane = tid & 63, wid = tid >> 6;
  const int l15 = lane & 15, g = lane >> 4;
  const int mbase = blockIdx.x * 16;
  const int nbase = wid * 64;

  int arow = mbase + l15; if (arow > M - 1) arow = M - 1;
  const int b = arow / SEQ, q = arow - b * SEQ;

  float invLh[8];
  #pragma unroll
  for (int h = 0; h < 8; ++h) {
    const size_t lb = (size_t)(b * 8 + h) * SEQ + q;
    invLh[h] = 1.f / (Lp[lb] + Lp[lb + (size_t)16 * SEQ]
                              + Lp[lb + (size_t)32 * SEQ]);
  }
  const size_t ob0 = ((size_t)(b * 8) * SEQ + q) * 32 + g * 8;
  const bf16_t* bp = Wt + (size_t)(nbase + l15) * 256 + g * 8;

  f32x4 acc[4];
  #pragma unroll
  for (int j = 0; j < 4; ++j) acc[j] = (f32x4){0.f,0.f,0.f,0.f};

  #pragma unroll
  for (int kk = 0; kk < 256; kk += 32) {
    const int h = kk >> 5;
    const size_t ob = ob0 + (size_t)h * (SEQ * 32);
    bf16x8 o0 = *(const bf16x8*)(Op0 + ob);
    bf16x8 o1 = *(const bf16x8*)(Op1 + ob);
    bf16x8 o2 = *(const bf16x8*)(Op2 + ob);
    const float inv = invLh[h];
    bf16x8 a;
    #pragma unroll
    for (int j = 0; j < 8; ++j)
      a[j] = (__bf16)(((float)o0[j] + (float)o1[j] + (float)o2[j]) * inv);
    #pragma unroll
    for (int ct = 0; ct < 4; ++ct) {
      bf16x8 bfr = *(const bf16x8*)(bp + (size_t)ct * 16 * 256 + kk);
      acc[ct] = mfma16(a, bfr, acc[ct]);
    }
  }

  float x[4][4];
  float xs[4] = {0.f,0.f,0.f,0.f}, xq[4] = {0.f,0.f,0.f,0.f};
  #pragma unroll
  for (int ct = 0; ct < 4; ++ct) {
    const int col = nbase + ct * 16 + l15;
    const float bv = bias[col];
    #pragma unroll
    for (int r = 0; r < 4; ++r) {
      int row = mbase + g * 4 + r; if (row > M - 1) row = M - 1;
      float v = acc[ct][r] + bv + (float)resid[(size_t)row * EMB + col];
      x[ct][r] = v;
      xs[r] += v; xq[r] += v * v;
    }
  }
  #pragma unroll
  for (int r = 0; r < 4; ++r) {
    #pragma unroll
    for (int m = 1; m < 16; m <<= 1) {
      xs[r] += __shfl_xor(xs[r], m);
      xq[r] += __shfl_xor(xq[r], m);
    }
  }
  if (l15 == 0) {
    #pragma unroll
    for (int r = 0; r < 4; ++r) {
      red[g * 4 + r][wid][0] = xs[r];
      red[g * 4 + r][wid][1] = xq[r];
    }
  }
  __syncthreads();
  #pragma unroll
  for (int r = 0; r < 4; ++r) {
    const int rl = g * 4 + r;
    const float S = red[rl][0][0] + red[rl][1][0] + red[rl][2][0] + red[rl][3][0];
    const float Q = red[rl][0][1] + red[rl][1][1] + red[rl][2][1] + red[rl][3][1];
    const float mean = S * (1.f / EMB);
    const float var = Q * (1.f / EMB) - mean * mean;
    const float rstd = rsqrtf(var + 1e-5f);
    const int row = mbase + rl;
    if (row < M) {
      #pragma unroll
      for (int ct = 0; ct < 4; ++ct) {
        const int col = nbase + ct * 16 + l15;
        OutB[(size_t)row * EMB + col] =
            (bf16_t)((x[ct][r] - mean) * rstd * gw[col] + bw[col]);
      }
    }
  }
}

// -------- fused GEMM (N=256) + bias + residual + LayerNorm (mfma16) ---------
template<int K>
__global__ __launch_bounds__(256) void gemm_ln_kernel(
    const bf16_t* __restrict__ A, const bf16_t* __restrict__ Wt,
    const float* __restrict__ bias, const bf16_t* __restrict__ resid,
    const float* __restrict__ gw, const float* __restrict__ bw,
    bf16_t* __restrict__ OutB, float* __restrict__ OutF, int M)
{
  __shared__ float red[16][4][2];
  const int tid = threadIdx.x;
  const int lane = tid & 63, wid = tid >> 6;
  const int l15 = lane & 15, g = lane >> 4;
  const int mbase = blockIdx.x * 16;
  const int nbase = wid * 64;

  int arow = mbase + l15; if (arow > M - 1) arow = M - 1;
  const bf16_t* ap = A + (size_t)arow * K + g * 8;
  const bf16_t* bp = Wt + (size_t)(nbase + l15) * K + g * 8;

  f32x4 acc[4];
  #pragma unroll
  for (int j = 0; j < 4; ++j) acc[j] = (f32x4){0.f,0.f,0.f,0.f};

  #pragma unroll
  for (int kk = 0; kk < K; kk += 32) {
    bf16x8 a = *(const bf16x8*)(ap + kk);
    #pragma unroll
    for (int ct = 0; ct < 4; ++ct) {
      bf16x8 bfr = *(const bf16x8*)(bp + (size_t)ct * 16 * K + kk);
      acc[ct] = mfma16(a, bfr, acc[ct]);
    }
  }

  float x[4][4];
  float xs[4] = {0.f,0.f,0.f,0.f}, xq[4] = {0.f,0.f,0.f,0.f};
  #pragma unroll
  for (int ct = 0; ct < 4; ++ct) {
    const int col = nbase + ct * 16 + l15;
    const float bv = bias[col];
    #pragma unroll
    for (int r = 0; r < 4; ++r) {
      int row = mbase + g * 4 + r; if (row > M - 1) row = M - 1;
      float v = acc[ct][r] + bv + (float)resid[(size_t)row * EMB + col];
      x[ct][r] = v;
      xs[r] += v; xq[r] += v * v;
    }
  }
  #pragma unroll
  for (int r = 0; r < 4; ++r) {
    #pragma unroll
    for (int m = 1; m < 16; m <<= 1) {
      xs[r] += __shfl_xor(xs[r], m);
      xq[r] += __shfl_xor(xq[r], m);
    }
  }
  if (l15 == 0) {
    #pragma unroll
    for (int r = 0; r < 4; ++r) {
      red[g * 4 + r][wid][0] = xs[r];
      red[g * 4 + r][wid][1] = xq[r];
    }
  }
  __syncthreads();
  #pragma unroll
  for (int r = 0; r < 4; ++r) {
    const int rl = g * 4 + r;
    const float S = red[rl][0][0] + red[rl][1][0] + red[rl][2][0] + red[rl][3][0];
    const float Q = red[rl][0][1] + red[rl][1][1] + red[rl][2][1] + red[rl][3][1];
    const float mean = S * (1.f / EMB);
    const float var = Q * (1.f / EMB) - mean * mean;
    const float rstd = rsqrtf(var + 1e-5f);
    const int row = mbase + rl;
    if (row < M) {
      #pragma unroll
      for (int ct = 0; ct < 4; ++ct) {
        const int col = nbase + ct * 16 + l15;
        const float y = (x[ct][r] - mean) * rstd * gw[col] + bw[col];
        if (OutF) OutF[(size_t)row * EMB + col] = y;
        else      OutB[(size_t)row * EMB + col] = (bf16_t)y;
      }
    }
  }
}

// ---------------- flash attention: barrier-free, no LDS ----------------------
// grid: 480 blocks = 8 XCD x 60 (bijective swizzle; each XCD owns 2 bh x 3
// splits). block 256 = 4 fully independent waves; wave = 64 q rows (X/Y).
// V fragments loaded directly from global in mfma B-operand layout:
// vf[e] = V[kv0 + 8*hi + e][d = lane&31] -- lanes 0..31 read consecutive d,
// so each scalar bf16 load coalesces into 2x64B segments, L2-resident and
// shared across the group's 10 q-blocks. No LDS, no __syncthreads.
__global__ __launch_bounds__(256, 2) void attn_part_kernel(
    const bf16_t* __restrict__ Qm, const bf16_t* __restrict__ Km,
    const bf16_t* __restrict__ Vm, bf16_t* __restrict__ Op0,
    bf16_t* __restrict__ Op1, bf16_t* __restrict__ Op2,
    float* __restrict__ Lp)
{
  const int tid = threadIdx.x;
  const int lane = tid & 63, wid = tid >> 6;
  const int q32 = lane & 31, hi = lane >> 5;

  // XCD-pinned decode (480 = 8 XCD * 60, bijective)
  const int n = blockIdx.x;
  const int vid = (n & 7) * 60 + (n >> 3);
  const int grp = vid / 10;          // 0..47 = bh*3 + split
  const int sub = vid - grp * 10;    // 0..9 q-block
  const int bh = grp / 3;            // 0..15
  const int split = grp - bh * 3;    // 0..2

  const size_t qoff = (size_t)(bh >> 3) * SEQ * EMB + (bh & 7) * HD;
  const int kv_begin = split * SPLITLEN;
  const int kv_end = min(kv_begin + SPLITLEN, SEQ);

  const int qbase = sub * 256 + wid * 64;
  const int qrX = min(qbase + q32, SEQ - 1);
  const int qrY = min(qbase + 32 + q32, SEQ - 1);
  const bf16x8 qfaX = *(const bf16x8*)(Qm + qoff + (size_t)qrX * EMB + hi * 8);
  const bf16x8 qfbX = *(const bf16x8*)(Qm + qoff + (size_t)qrX * EMB + 16 + hi * 8);
  const bf16x8 qfaY = *(const bf16x8*)(Qm + qoff + (size_t)qrY * EMB + hi * 8);
  const bf16x8 qfbY = *(const bf16x8*)(Qm + qoff + (size_t)qrY * EMB + 16 + hi * 8);

  f32x16 accAX = {}, accBX = {}, accAY = {}, accBY = {};
  float lsumX = 0.f, lsumY = 0.f;

  // stepped global pointers: K rows by q32-lane; V per-lane column d=q32
  const bf16_t* kp = Km + qoff + (size_t)(kv_begin + q32) * EMB + hi * 8;
  const bf16_t* vp = Vm + qoff + (size_t)kv_begin * EMB + q32 + (size_t)hi * 8 * EMB;

  // V fragment loader: f1[e] = vp'[(e)*EMB], f2[e] = vp'[(16+e)*EMB]
#define LOADV(f1, f2, base)                                                    \
    {                                                                          \
      _Pragma("unroll")                                                        \
      for (int e = 0; e < 8; ++e) {                                            \
        f1[e] = (base)[(size_t)e * EMB];                                       \
        f2[e] = (base)[(size_t)(16 + e) * EMB];                                \
      }                                                                        \
    }

  // prologue: pair 0 loads
  bf16x8 kaA = *(const bf16x8*)kp;
  bf16x8 kbA = *(const bf16x8*)(kp + 16);
  bf16x8 kaB = *(const bf16x8*)(kp + 32 * EMB);
  bf16x8 kbB = *(const bf16x8*)(kp + 32 * EMB + 16);
  kp += 64 * EMB;
  bf16x8 vf1A, vf2A, vf1B, vf2B;
  LOADV(vf1A, vf2A, vp)
  LOADV(vf1B, vf2B, vp + 32 * EMB)
  vp += 64 * EMB;

#define TREE16(dst, p)                                                         \
    {                                                                          \
      float t0 = p[0] + p[1],  t1 = p[2] + p[3];                               \
      float t2 = p[4] + p[5],  t3 = p[6] + p[7];                               \
      float t4 = p[8] + p[9],  t5 = p[10] + p[11];                             \
      float t6 = p[12] + p[13], t7 = p[14] + p[15];                            \
      float u0 = t0 + t1, u1 = t2 + t3, u2 = t4 + t5, u3 = t6 + t7;            \
      dst = (u0 + u1) + (u2 + u3);                                             \
    }

#define SOFTPACK(p, f1, f2)                                                    \
    {                                                                          \
      u32 w0 = pack2(p[0], p[1]),   w1 = pack2(p[2], p[3]);                    \
      u32 w2 = pack2(p[4], p[5]),   w3 = pack2(p[6], p[7]);                    \
      u32 w4 = pack2(p[8], p[9]),   w5 = pack2(p[10], p[11]);                  \
      u32 w6 = pack2(p[12], p[13]), w7 = pack2(p[14], p[15]);                  \
      asm("v_permlane32_swap_b32 %0, %1" : "+v"(w0), "+v"(w2));                \
      asm("v_permlane32_swap_b32 %0, %1" : "+v"(w1), "+v"(w3));                \
      asm("v_permlane32_swap_b32 %0, %1" : "+v"(w4), "+v"(w6));                \
      asm("v_permlane32_swap_b32 %0, %1" : "+v"(w5), "+v"(w7));                \
      f1.x = w0; f1.y = w1; f1.z = w2; f1.w = w3;                              \
      f2.x = w4; f2.y = w5; f2.z = w6; f2.w = w7;                              \
    }

  // one softmax chain: s -> p (exp2, optional tail mask) -> lsum -> packed f1/f2
#define CHAIN(s, MASKED, kv0, lsum, f1, f2)                                    \
    {                                                                          \
      float p[16];                                                             \
      _Pragma("unroll")                                                        \
      for (int r = 0; r < 16; ++r) p[r] = __builtin_amdgcn_exp2f(s[r]);        \
      if (MASKED) {                                                            \
        _Pragma("unroll")                                                      \
        for (int r = 0; r < 16; ++r) {                                         \
          const int kvg = (kv0) + (r & 3) + ((r >> 2) << 3) + hi * 4;          \
          if (kvg >= kv_end) p[r] = 0.f;                                       \
        }                                                                      \
      }                                                                        \
      float ps;                                                                \
      TREE16(ps, p)                                                            \
      lsum += ps;                                                              \
      SOFTPACK(p, f1, f2)                                                      \
    }

#define ATTN_PAIR(P, MASKED, PREFETCH)                                         \
  {                                                                            \
    bf16x8 kaAn, kbAn, kaBn, kbBn;                                             \
    bf16x8 vf1An, vf2An, vf1Bn, vf2Bn;                                         \
    if (PREFETCH) {                                                            \
      kaAn = *(const bf16x8*)kp;                                               \
      kbAn = *(const bf16x8*)(kp + 16);                                        \
      kaBn = *(const bf16x8*)(kp + 32 * EMB);                                  \
      kbBn = *(const bf16x8*)(kp + 32 * EMB + 16);                             \
      kp += 64 * EMB;                                                          \
      LOADV(vf1An, vf2An, vp)                                                  \
      LOADV(vf1Bn, vf2Bn, vp + 32 * EMB)                                       \
      vp += 64 * EMB;                                                          \
    }                                                                          \
    f32x16 sAX = {}, sBX = {}, sAY = {}, sBY = {};                             \
    sAX = mfma32(kaA, qfaX, sAX);                                              \
    sBX = mfma32(kaB, qfaX, sBX);                                              \
    sAY = mfma32(kaA, qfaY, sAY);                                              \
    sBY = mfma32(kaB, qfaY, sBY);                                              \
    sAX = mfma32(kbA, qfbX, sAX);                                              \
    sBX = mfma32(kbB, qfbX, sBX);                                              \
    sAY = mfma32(kbA, qfbY, sAY);                                              \
    sBY = mfma32(kbB, qfbY, sBY);                                              \
    const int kvA = kv_begin + (((P) << 1) << 5);                              \
    const int kvB = kvA + 32;                                                  \
    u32x4 f1AX, f2AX, f1BX, f2BX, f1AY, f2AY, f1BY, f2BY;                      \
    CHAIN(sAX, MASKED, kvA, lsumX, f1AX, f2AX)                                 \
    CHAIN(sBX, MASKED, kvB, lsumX, f1BX, f2BX)                                 \
    CHAIN(sAY, MASKED, kvA, lsumY, f1AY, f2AY)                                 \
    CHAIN(sBY, MASKED, kvB, lsumY, f1BY, f2BY)                                 \
    accAX = mfma32(*(bf16x8*)&f1AX, vf1A, accAX);                              \
    accBX = mfma32(*(bf16x8*)&f1BX, vf1B, accBX);                              \
    accAY = mfma32(*(bf16x8*)&f1AY, vf1A, accAY);                              \
    accBY = mfma32(*(bf16x8*)&f1BY, vf1B, accBY);                              \
    accAX = mfma32(*(bf16x8*)&f2AX, vf2A, accAX);                              \
    accBX = mfma32(*(bf16x8*)&f2BX, vf2B, accBX);                              \
    accAY = mfma32(*(bf16x8*)&f2AY, vf2A, accAY);                              \
    accBY = mfma32(*(bf16x8*)&f2BY, vf2B, accBY);                              \
    if (PREFETCH) {                                                            \
      kaA = kaAn; kbA = kbAn; kaB = kaBn; kbB = kbBn;                          \
      vf1A = vf1An; vf2A = vf2An; vf1B = vf1Bn; vf2B = vf2Bn;                  \
    }                                                                          \
  }

  #pragma unroll
  for (int P = 0; P < NPAIR - 1; ++P) ATTN_PAIR(P, 0, 1)
  ATTN_PAIR(NPAIR - 1, 1, 0)
#undef ATTN_PAIR
#undef CHAIN
#undef SOFTPACK
#undef TREE16
#undef LOADV

  lsumX += __shfl_xor(lsumX, 32);
  lsumY += __shfl_xor(lsumY, 32);
  bf16_t* Opx = (split == 0) ? Op0 : (split == 1) ? Op1 : Op2;
  const size_t obase = (size_t)bh * SEQ;
  const size_t lbase = ((size_t)split * 16 + bh) * SEQ;
  #pragma unroll
  for (int r = 0; r < 16; ++r) {
    const int qX = qbase + (r & 3) + ((r >> 2) << 3) + hi * 4;
    const int qY = qX + 32;
    if (qX < SEQ) Opx[(obase + qX) * 32 + q32] = (bf16_t)(accAX[r] + accBX[r]);
    if (qY < SEQ) Opx[(obase + qY) * 32 + q32] = (bf16_t)(accAY[r] + accBY[r]);
  }
  if (lane < 32) {
    const int qX = qbase + lane, qY = qX + 32;
    if (qX < SEQ) Lp[lbase + qX] = lsumX;
    if (qY < SEQ) Lp[lbase + qY] = lsumY;
  }
}

// ---------------- merge partials + residual + LayerNorm (temporal) ----------
__global__ __launch_bounds__(256) void merge_kernel(
    const bf16_t* __restrict__ Op0, const bf16_t* __restrict__ Op1,
    const bf16_t* __restrict__ Op2, const float* __restrict__ Lp,
    const bf16_t* __restrict__ resid, const float* __restrict__ gw,
    const float* __restrict__ bw, bf16_t* __restrict__ out)
{
  const int lane = threadIdx.x & 63, wid = threadIdx.x >> 6;
  const int row = blockIdx.x * 4 + wid;        // 0..4999
  const int b = row / SEQ, q = row - b * SEQ;
  const int h = lane >> 3, dl = (lane & 7) * 4;
  const int bh = b * 8 + h;

  const size_t lb = (size_t)bh * SEQ + q;
  const float L = Lp[lb] + Lp[lb + (size_t)16 * SEQ] + Lp[lb + (size_t)32 * SEQ];
  const float invL = 1.f / L;

  const size_t pb = ((size_t)bh * SEQ + q) * 32 + dl;
  bf16x4 o0 = *(const bf16x4*)(Op0 + pb);
  bf16x4 o1 = *(const bf16x4*)(Op1 + pb);
  bf16x4 o2 = *(const bf16x4*)(Op2 + pb);

  const size_t base = (size_t)row * EMB + lane * 4;
  bf16x4 rv = *(const bf16x4*)(resid + base);
  float x[4], s = 0.f, sq = 0.f;
  #pragma unroll
  for (int j = 0; j < 4; ++j) {
    x[j] = ((float)o0[j] + (float)o1[j] + (float)o2[j]) * invL + (float)rv[j];
    s += x[j]; sq += x[j] * x[j];
  }
  #pragma unroll
  for (int m = 1; m < 64; m <<= 1) { s += __shfl_xor(s, m); sq += __shfl_xor(sq, m); }
  const float mean = s * (1.f / EMB);
  const float var = sq * (1.f / EMB) - mean * mean;
  const float rstd = rsqrtf(var + 1e-5f);
  float4 gv = *(const float4*)(gw + lane * 4);
  float4 bv = *(const float4*)(bw + lane * 4);
  bf16x4 ov;
  ov[0] = (__bf16)((x[0] - mean) * rstd * gv.x + bv.x);
  ov[1] = (__bf16)((x[1] - mean) * rstd * gv.y + bv.y);
  ov[2] = (__bf16)((x[2] - mean) * rstd * gv.z + bv.z);
  ov[3] = (__bf16)((x[3] - mean) * rstd * gv.w + bv.w);
  *(bf16x4*)(out + base) = ov;
}

// ---------------- launch ----------------
extern "C" void kernel_launch(void* const* d_in, const int* in_sizes, int n_in,
                              void* d_out, int out_size, void* d_ws, size_t ws_size,
                              hipStream_t stream)
{
  (void)in_sizes; (void)n_in; (void)out_size; (void)ws_size;
  const float* prev  = (const float*)d_in[0];
  const float* query = (const float*)d_in[1];
  const float* img   = (const float*)d_in[2];
  const float* t_wq  = (const float*)d_in[3];
  const float* t_wk  = (const float*)d_in[4];
  const float* t_wv  = (const float*)d_in[5];
  const float* s_wq  = (const float*)d_in[6];
  const float* s_wk  = (const float*)d_in[7];
  const float* s_wv  = (const float*)d_in[8];
  const float* s_wo  = (const float*)d_in[9];
  const float* s_bo  = (const float*)d_in[10];
  const float* n1g = (const float*)d_in[11];
  const float* n1b = (const float*)d_in[12];
  const float* n2g = (const float*)d_in[13];
  const float* n2b = (const float*)d_in[14];
  const float* n3g = (const float*)d_in[15];
  const float* n3b = (const float*)d_in[16];
  const float* ffw1 = (const float*)d_in[17];
  const float* ffb1 = (const float*)d_in[18];
  const float* ffw2 = (const float*)d_in[19];
  const float* ffb2 = (const float*)d_in[20];

  bf16_t* ws   = (bf16_t*)d_ws;
  bf16_t* WT   = ws;                    // weights bf16 transposed
  bf16_t* WTF1 = ws + 458752;
  bf16_t* WTF2 = ws + 589824;
  bf16_t* qbf = ws + 720896;
  bf16_t* pbf = qbf + 1280000;
  bf16_t* ibf = pbf + 1280000;
  bf16_t* qb = ibf + 1280000;
  bf16_t* kb = qb + 1280000;
  bf16_t* vb = kb + 1280000;            // after attn1: reused as x2
  bf16_t* ab = vb + 1280000;            // Op0 (per-split attn partials)
  bf16_t* x1 = ab + 1280000;
  bf16_t* cb = x1 + 1280000;            // Op1
  bf16_t* x2r = cb + 1280000;           // Op2 (old x2 region)
  bf16_t* hb = x2r + 1280000;           // 5000x512; first: spatial K/V
  bf16_t* fb = hb + 2560000;            // OOB-read landing zone (finite)
  float* outp = (float*)d_out;

  bf16_t* Op0 = ab;
  bf16_t* Op1 = cb;
  bf16_t* Op2 = x2r;
  bf16_t* kb2 = hb;                     // spatial K (dead before FFN writes hb)
  bf16_t* vb2 = hb + 1280000;           // spatial V
  bf16_t* X2 = vb;                      // post-attn x2 (vb dead after attn1)
  float*  Lp = (float*)pbf;             // 3*16*2500 floats (pbf dead post-proj5)

  const float log2e = 1.4426950408889634f;
  const float qscT = log2e * (1.f / 16.f);
  const float qscS = log2e * 0.17677669529663687f;

  dim3 blk(256);
  prep_kernel<<<1115, blk, 0, stream>>>(t_wq, t_wk, t_wv, s_wq, s_wk, s_wv,
                                        s_wo, ffw1, ffw2, ws,
                                        query, prev, img, qbf, pbf, ibf);

  dim3 gP5(40, 4, 5), gP1(40, 4), gG512(40, 8);
  // temporal Q/K/V + spatial K/V (spatial K/V only need prep)
  proj5_kernel<<<gP5, blk, 0, stream>>>(qbf, pbf, ibf, WT,
                                        qb, kb, vb, kb2, vb2, qscT);
  attn_part_kernel<<<480, blk, 0, stream>>>(qb, kb, vb, Op0, Op1, Op2, Lp);
  merge_kernel<<<1250, blk, 0, stream>>>(Op0, Op1, Op2, Lp, qbf, n1g, n1b, x1);
  // spatial Q projection
  projq_kernel<<<gP1, blk, 0, stream>>>(x1, WT + 196608, qb, qscS);
  attn_part_kernel<<<480, blk, 0, stream>>>(qb, kb2, vb2, Op0, Op1, Op2, Lp);
  // fused: merge partials + s_wo GEMM + bias + residual(x1) + LN(n2) -> X2
  gemm_ln_merge_kernel<<<313, blk, 0, stream>>>(Op0, Op1, Op2, Lp,
                                                WT + 393216, s_bo, x1,
                                                n2g, n2b, X2, MTOT);
  // FFN
  gemm_relu_kernel<<<gG512, blk, 0, stream>>>(X2, WTF1, ffb1, hb, MTOT, 512);
  gemm_ln_kernel<512><<<313, blk, 0, stream>>>(hb, WTF2, ffb2, X2,
                                               n3g, n3b, nullptr, outp, MTOT);
  (void)fb;
}

// Round 12
// 167.493 us; speedup vs baseline: 1.0215x; 1.0215x over previous
//
#include <hip/hip_runtime.h>
#include <hip/hip_bf16.h>
#include <stdint.h>

// BevFormer block: temporal MHA + LN, spatial cross-MHA(+proj) + LN, FFN + LN.
// I/O f32; internal bf16 MFMA + f32 accum. Flash attention (KVSPLIT=3,
// fixed-max exp2 softmax, 32x32x16 MFMA, in-register P via permlane32_swap,
// XCD-pinned swizzle, 2 kv-tiles x 2 q-tiles/iter, LDS V staging + 1 barrier
// per pair -- round-11 barrier-free variant REVERTED, it regressed), mfma32
// GEMM bodies, fused GEMM+LN tails, merge2 fused into s_wo GEMM.
// Round 12: softmax denominator via MFMA row-sum (accS = mfma(P_frag, ones))
// -- replaces 60 VALU tree-adds/pair with 8 mfma32 on the 5%-utilized MFMA
// pipe; denominator now bf16-consistent with the PV numerator.

typedef __bf16 bf16_t;
typedef __bf16 bf16x8 __attribute__((ext_vector_type(8)));
typedef __bf16 bf16x4 __attribute__((ext_vector_type(4)));
typedef float  f32x4  __attribute__((ext_vector_type(4)));
typedef float  f32x16 __attribute__((ext_vector_type(16)));
typedef uint32_t u32;
typedef uint32_t u32x4 __attribute__((ext_vector_type(4)));

#define NB   2
#define SEQ  2500
#define EMB  256
#define NH   8
#define HD   32
#define MTOT (NB*SEQ)
#define KVSPLIT 3
#define SPLITLEN 834       // splits: [0,834) [834,1668) [1668,2500)
#define NPAIR 14           // 14 pairs = 28 tiles = 896 kv slots (tail masked)

static __device__ __forceinline__ f32x4 mfma16(bf16x8 a, bf16x8 b, f32x4 c) {
  return __builtin_amdgcn_mfma_f32_16x16x32_bf16(a, b, c, 0, 0, 0);
}
static __device__ __forceinline__ f32x16 mfma32(bf16x8 a, bf16x8 b, f32x16 c) {
  return __builtin_amdgcn_mfma_f32_32x32x16_bf16(a, b, c, 0, 0, 0);
}
static __device__ __forceinline__ u32 pack2(float a, float b) {
  union { __bf16 h; unsigned short s; } x, y;
  x.h = (__bf16)a; y.h = (__bf16)b;
  return (u32)x.s | ((u32)y.s << 16);
}

// ---------------- prep: weight transpose->bf16 + activation cvt ----------------
__global__ __launch_bounds__(256) void prep_kernel(
    const float* s0, const float* s1, const float* s2, const float* s3,
    const float* s4, const float* s5, const float* s6, const float* s7,
    const float* s8, bf16_t* wt,
    const float* aq, const float* ap, const float* ai,
    bf16_t* dq, bf16_t* dp, bf16_t* di)
{
  int b = blockIdx.x;
  if (b < 176) {
    const float* src; int R, C, tl; size_t doff;
    if (b < 112) {
      int mi = b >> 4; tl = b & 15; R = 256; C = 256; doff = (size_t)mi * 65536;
      switch (mi) {
        case 0: src = s0; break; case 1: src = s1; break; case 2: src = s2; break;
        case 3: src = s3; break; case 4: src = s4; break; case 5: src = s5; break;
        default: src = s6;
      }
    } else if (b < 144) { tl = b - 112; R = 256; C = 512; doff = 458752; src = s7; }
    else                { tl = b - 144; R = 512; C = 256; doff = 589824; src = s8; }
    const int tpr = C >> 6;
    const int tr = tl / tpr, tc = tl % tpr;
    bf16_t* dst = wt + doff;
    #pragma unroll
    for (int i = 0; i < 16; ++i) {
      int lin = i * 256 + threadIdx.x;
      int lr = lin >> 6, lc = lin & 63;
      int rr = tr * 64 + lr, cc = tc * 64 + lc;
      dst[(size_t)cc * R + rr] = (__bf16)src[(size_t)rr * C + cc];
    }
    return;
  }
  int idx = b - 176;
  int t = idx / 313, r = idx % 313;
  const float* src = (t == 0) ? aq : (t == 1) ? ap : ai;
  bf16_t* dst = (t == 0) ? dq : (t == 1) ? dp : di;
  #pragma unroll
  for (int k = 0; k < 4; ++k) {
    int i = r * 1024 + k * 256 + threadIdx.x;
    if (i < 320000) {
      float4 v = ((const float4*)src)[i];
      bf16x4 o;
      o[0] = (__bf16)v.x; o[1] = (__bf16)v.y; o[2] = (__bf16)v.z; o[3] = (__bf16)v.w;
      ((bf16x4*)dst)[i] = o;
    }
  }
}

// -------- mfma32 GEMM body: wave = 32 rows x 64 cols; block = 4 waves = 128 rows.
template<int K>
static __device__ __forceinline__ void gemm32_body(
    const bf16_t* __restrict__ A, const bf16_t* __restrict__ Wt,
    const float* __restrict__ bias, bf16_t* __restrict__ Cout,
    int M, int N, int relu, float cscale, int bx, int by)
{
  const int tid = threadIdx.x;
  const int lane = tid & 63, wid = tid >> 6;
  const int l31 = lane & 31, hi = lane >> 5;
  const int mbase = bx * 128 + wid * 32;
  const int nbase = by * 64;

  int arow = mbase + l31; if (arow > M - 1) arow = M - 1;
  const bf16_t* ap = A + (size_t)arow * K + hi * 8;
  const bf16_t* bp = Wt + (size_t)(nbase + l31) * K + hi * 8;

  f32x16 acc0 = {}, acc1 = {};
  #pragma unroll
  for (int kk = 0; kk < K; kk += 16) {
    bf16x8 a  = *(const bf16x8*)(ap + kk);
    bf16x8 b0 = *(const bf16x8*)(bp + kk);
    bf16x8 b1 = *(const bf16x8*)(bp + (size_t)32 * K + kk);
    acc0 = mfma32(a, b0, acc0);
    acc1 = mfma32(a, b1, acc1);
  }
  #pragma unroll
  for (int r = 0; r < 16; ++r) {
    const int row = mbase + (r & 3) + ((r >> 2) << 3) + hi * 4;
    if (row < M) {
      const int c0 = nbase + l31;
      const int c1 = nbase + 32 + l31;
      float v0 = acc0[r] * cscale + (bias ? bias[c0] : 0.f);
      float v1 = acc1[r] * cscale + (bias ? bias[c1] : 0.f);
      if (relu) { v0 = fmaxf(v0, 0.f); v1 = fmaxf(v1, 0.f); }
      Cout[(size_t)row * N + c0] = (bf16_t)v0;
      Cout[(size_t)row * N + c1] = (bf16_t)v1;
    }
  }
}

// x2 @ WTF1 (+bias, relu), N=512, K=256
__global__ __launch_bounds__(256) void gemm_relu_kernel(
    const bf16_t* __restrict__ A, const bf16_t* __restrict__ Wt,
    const float* __restrict__ bias, bf16_t* __restrict__ Cout,
    int M, int N)
{
  gemm32_body<256>(A, Wt, bias, Cout, M, N, 1, 1.f, blockIdx.x, blockIdx.y);
}

// five batched projections: temporal Q/K/V + spatial K/V (spatial K/V only
// depend on prep, so they ride the first launch). qsc applied to z==0.
__global__ __launch_bounds__(256) void proj5_kernel(
    const bf16_t* qbf, const bf16_t* pbf, const bf16_t* ibf,
    const bf16_t* WT,
    bf16_t* tq, bf16_t* tk, bf16_t* tv, bf16_t* sk, bf16_t* sv, float qsc)
{
  const int z = blockIdx.z;
  const bf16_t* A; const bf16_t* W; bf16_t* C; float cs = 1.f;
  switch (z) {
    case 0:  A = qbf; W = WT;          C = tq; cs = qsc; break;
    case 1:  A = pbf; W = WT + 65536;  C = tk; break;
    case 2:  A = pbf; W = WT + 131072; C = tv; break;
    case 3:  A = ibf; W = WT + 262144; C = sk; break;
    default: A = ibf; W = WT + 327680; C = sv; break;
  }
  gemm32_body<256>(A, W, nullptr, C, MTOT, 256, 0, cs, blockIdx.x, blockIdx.y);
}

// single scaled projection: spatial Q = x1 @ s_wq * qscS
__global__ __launch_bounds__(256) void projq_kernel(
    const bf16_t* __restrict__ A, const bf16_t* __restrict__ W,
    bf16_t* __restrict__ C, float sc)
{
  gemm32_body<256>(A, W, nullptr, C, MTOT, 256, 0, sc, blockIdx.x, blockIdx.y);
}

// -------- fused [merge partials] + GEMM(s_wo) + bias + residual + LN --------
__global__ __launch_bounds__(256) void gemm_ln_merge_kernel(
    const bf16_t* __restrict__ Op0, const bf16_t* __restrict__ Op1,
    const bf16_t* __restrict__ Op2, const float* __restrict__ Lp,
    const bf16_t* __restrict__ Wt, const float* __restrict__ bias,
    const bf16_t* __restrict__ resid, const float* __restrict__ gw,
    const float* __restrict__ bw, bf16_t* __restrict__ OutB, int M)
{
  __shared__ float red[16][4][2];
  const int tid = threadIdx.x;
  const int lane = tid & 63, wid = tid >> 6;
  const int l15 = lane & 15, g = lane >> 4;
  const int mbase = blockIdx.x * 16;
  const int nbase = wid * 64;

  int arow = mbase + l15; if (arow > M - 1) arow = M - 1;
  const int b = arow / SEQ, q = arow - b * SEQ;

  float invLh[8];
  #pragma unroll
  for (int h = 0; h < 8; ++h) {
    const size_t lb = (size_t)(b * 8 + h) * SEQ + q;
    invLh[h] = 1.f / (Lp[lb] + Lp[lb + (size_t)16 * SEQ]
                              + Lp[lb + (size_t)32 * SEQ]);
  }
  const size_t ob0 = ((size_t)(b * 8) * SEQ + q) * 32 + g * 8;
  const bf16_t* bp = Wt + (size_t)(nbase + l15) * 256 + g * 8;

  f32x4 acc[4];
  #pragma unroll
  for (int j = 0; j < 4; ++j) acc[j] = (f32x4){0.f,0.f,0.f,0.f};

  #pragma unroll
  for (int kk = 0; kk < 256; kk += 32) {
    const int h = kk >> 5;
    const size_t ob = ob0 + (size_t)h * (SEQ * 32);
    bf16x8 o0 = *(const bf16x8*)(Op0 + ob);
    bf16x8 o1 = *(const bf16x8*)(Op1 + ob);
    bf16x8 o2 = *(const bf16x8*)(Op2 + ob);
    const float inv = invLh[h];
    bf16x8 a;
    #pragma unroll
    for (int j = 0; j < 8; ++j)
      a[j] = (__bf16)(((float)o0[j] + (float)o1[j] + (float)o2[j]) * inv);
    #pragma unroll
    for (int ct = 0; ct < 4; ++ct) {
      bf16x8 bfr = *(const bf16x8*)(bp + (size_t)ct * 16 * 256 + kk);
      acc[ct] = mfma16(a, bfr, acc[ct]);
    }
  }

  float x[4][4];
  float xs[4] = {0.f,0.f,0.f,0.f}, xq[4] = {0.f,0.f,0.f,0.f};
  #pragma unroll
  for (int ct = 0; ct < 4; ++ct) {
    const int col = nbase + ct * 16 + l15;
    const float bv = bias[col];
    #pragma unroll
    for (int r = 0; r < 4; ++r) {
      int row = mbase + g * 4 + r; if (row > M - 1) row = M - 1;
      float v = acc[ct][r] + bv + (float)resid[(size_t)row * EMB + col];
      x[ct][r] = v;
      xs[r] += v; xq[r] += v * v;
    }
  }
  #pragma unroll
  for (int r = 0; r < 4; ++r) {
    #pragma unroll
    for (int m = 1; m < 16; m <<= 1) {
      xs[r] += __shfl_xor(xs[r], m);
      xq[r] += __shfl_xor(xq[r], m);
    }
  }
  if (l15 == 0) {
    #pragma unroll
    for (int r = 0; r < 4; ++r) {
      red[g * 4 + r][wid][0] = xs[r];
      red[g * 4 + r][wid][1] = xq[r];
    }
  }
  __syncthreads();
  #pragma unroll
  for (int r = 0; r < 4; ++r) {
    const int rl = g * 4 + r;
    const float S = red[rl][0][0] + red[rl][1][0] + red[rl][2][0] + red[rl][3][0];
    const float Q = red[rl][0][1] + red[rl][1][1] + red[rl][2][1] + red[rl][3][1];
    const float mean = S * (1.f / EMB);
    const float var = Q * (1.f / EMB) - mean * mean;
    const float rstd = rsqrtf(var + 1e-5f);
    const int row = mbase + rl;
    if (row < M) {
      #pragma unroll
      for (int ct = 0; ct < 4; ++ct) {
        const int col = nbase + ct * 16 + l15;
        OutB[(size_t)row * EMB + col] =
            (bf16_t)((x[ct][r] - mean) * rstd * gw[col] + bw[col]);
      }
    }
  }
}

// -------- fused GEMM (N=256) + bias + residual + LayerNorm (mfma16) ---------
template<int K>
__global__ __launch_bounds__(256) void gemm_ln_kernel(
    const bf16_t* __restrict__ A, const bf16_t* __restrict__ Wt,
    const float* __restrict__ bias, const bf16_t* __restrict__ resid,
    const float* __restrict__ gw, const float* __restrict__ bw,
    bf16_t* __restrict__ OutB, float* __restrict__ OutF, int M)
{
  __shared__ float red[16][4][2];
  const int tid = threadIdx.x;
  const int lane = tid & 63, wid = tid >> 6;
  const int l15 = lane & 15, g = lane >> 4;
  const int mbase = blockIdx.x * 16;
  const int nbase = wid * 64;

  int arow = mbase + l15; if (arow > M - 1) arow = M - 1;
  const bf16_t* ap = A + (size_t)arow * K + g * 8;
  const bf16_t* bp = Wt + (size_t)(nbase + l15) * K + g * 8;

  f32x4 acc[4];
  #pragma unroll
  for (int j = 0; j < 4; ++j) acc[j] = (f32x4){0.f,0.f,0.f,0.f};

  #pragma unroll
  for (int kk = 0; kk < K; kk += 32) {
    bf16x8 a = *(const bf16x8*)(ap + kk);
    #pragma unroll
    for (int ct = 0; ct < 4; ++ct) {
      bf16x8 bfr = *(const bf16x8*)(bp + (size_t)ct * 16 * K + kk);
      acc[ct] = mfma16(a, bfr, acc[ct]);
    }
  }

  float x[4][4];
  float xs[4] = {0.f,0.f,0.f,0.f}, xq[4] = {0.f,0.f,0.f,0.f};
  #pragma unroll
  for (int ct = 0; ct < 4; ++ct) {
    const int col = nbase + ct * 16 + l15;
    const float bv = bias[col];
    #pragma unroll
    for (int r = 0; r < 4; ++r) {
      int row = mbase + g * 4 + r; if (row > M - 1) row = M - 1;
      float v = acc[ct][r] + bv + (float)resid[(size_t)row * EMB + col];
      x[ct][r] = v;
      xs[r] += v; xq[r] += v * v;
    }
  }
  #pragma unroll
  for (int r = 0; r < 4; ++r) {
    #pragma unroll
    for (int m = 1; m < 16; m <<= 1) {
      xs[r] += __shfl_xor(xs[r], m);
      xq[r] += __shfl_xor(xq[r], m);
    }
  }
  if (l15 == 0) {
    #pragma unroll
    for (int r = 0; r < 4; ++r) {
      red[g * 4 + r][wid][0] = xs[r];
      red[g * 4 + r][wid][1] = xq[r];
    }
  }
  __syncthreads();
  #pragma unroll
  for (int r = 0; r < 4; ++r) {
    const int rl = g * 4 + r;
    const float S = red[rl][0][0] + red[rl][1][0] + red[rl][2][0] + red[rl][3][0];
    const float Q = red[rl][0][1] + red[rl][1][1] + red[rl][2][1] + red[rl][3][1];
    const float mean = S * (1.f / EMB);
    const float var = Q * (1.f / EMB) - mean * mean;
    const float rstd = rsqrtf(var + 1e-5f);
    const int row = mbase + rl;
    if (row < M) {
      #pragma unroll
      for (int ct = 0; ct < 4; ++ct) {
        const int col = nbase + ct * 16 + l15;
        const float y = (x[ct][r] - mean) * rstd * gw[col] + bw[col];
        if (OutF) OutF[(size_t)row * EMB + col] = y;
        else      OutB[(size_t)row * EMB + col] = (bf16_t)y;
      }
    }
  }
}

// ---------------- flash attention, 32x32x16 MFMA, 2 kv-tiles x 2 q-tiles -----
// grid: 480 blocks = 8 XCD x 60 (bijective swizzle; each XCD owns 2 bh x 3
// splits). block 256 = 4 waves; wave = 64 q rows (two 32-row tiles X/Y).
// LDS V staging, one barrier per pair (round-10 structure). Softmax
// denominator via MFMA row-sum against an all-ones B fragment (accS).
__global__ __launch_bounds__(256, 2) void attn_part_kernel(
    const bf16_t* __restrict__ Qm, const bf16_t* __restrict__ Km,
    const bf16_t* __restrict__ Vm, bf16_t* __restrict__ Op0,
    bf16_t* __restrict__ Op1, bf16_t* __restrict__ Op2,
    float* __restrict__ Lp)
{
  __shared__ bf16_t Vt[4][32][40];   // V^T, col-rotated: Vt[d][(kv + 8*(d>>3))&31]

  const int tid = threadIdx.x;
  const int lane = tid & 63, wid = tid >> 6;
  const int q32 = lane & 31, hi = lane >> 5;

  // XCD-pinned decode (480 = 8 XCD * 60, bijective)
  const int n = blockIdx.x;
  const int vid = (n & 7) * 60 + (n >> 3);
  const int grp = vid / 10;          // 0..47 = bh*3 + split
  const int sub = vid - grp * 10;    // 0..9 q-block
  const int bh = grp / 3;            // 0..15
  const int split = grp - bh * 3;    // 0..2

  const size_t qoff = (size_t)(bh >> 3) * SEQ * EMB + (bh & 7) * HD;
  const int kv_begin = split * SPLITLEN;
  const int kv_end = min(kv_begin + SPLITLEN, SEQ);

  const int qbase = sub * 256 + wid * 64;
  const int qrX = min(qbase + q32, SEQ - 1);
  const int qrY = min(qbase + 32 + q32, SEQ - 1);
  const bf16x8 qfaX = *(const bf16x8*)(Qm + qoff + (size_t)qrX * EMB + hi * 8);
  const bf16x8 qfbX = *(const bf16x8*)(Qm + qoff + (size_t)qrX * EMB + 16 + hi * 8);
  const bf16x8 qfaY = *(const bf16x8*)(Qm + qoff + (size_t)qrY * EMB + hi * 8);
  const bf16x8 qfbY = *(const bf16x8*)(Qm + qoff + (size_t)qrY * EMB + 16 + hi * 8);

  f32x16 accAX = {}, accBX = {}, accAY = {}, accBY = {};
  f32x16 accSX = {}, accSY = {};     // MFMA row-sums: softmax denominators
  bf16x8 vones;
  #pragma unroll
  for (int j = 0; j < 8; ++j) vones[j] = (__bf16)1.0f;

  // V staging map: 256 threads, thread -> (kv, 4 d's)
  const int skv = tid >> 3;           // 0..31
  const int sd0 = (tid & 7) << 2;     // 0..28 step 4
  const int scc = (skv + ((sd0 >> 3) << 3)) & 31;

  // stepped global pointers
  const bf16_t* kp = Km + qoff + (size_t)(kv_begin + q32) * EMB + hi * 8;
  const bf16_t* vp = Vm + qoff + (size_t)(kv_begin + skv) * EMB + sd0;

  // prologue: pair 0 loads (tiles 0,1)
  bf16x4 vA = *(const bf16x4*)vp;
  bf16x4 vB = *(const bf16x4*)(vp + 32 * EMB);
  bf16x8 kaA = *(const bf16x8*)kp;
  bf16x8 kbA = *(const bf16x8*)(kp + 16);
  bf16x8 kaB = *(const bf16x8*)(kp + 32 * EMB);
  bf16x8 kbB = *(const bf16x8*)(kp + 32 * EMB + 16);
  kp += 64 * EMB;
  vp += 64 * EMB;

#define SOFTPACK(p, f1, f2)                                                    \
    {                                                                          \
      u32 w0 = pack2(p[0], p[1]),   w1 = pack2(p[2], p[3]);                    \
      u32 w2 = pack2(p[4], p[5]),   w3 = pack2(p[6], p[7]);                    \
      u32 w4 = pack2(p[8], p[9]),   w5 = pack2(p[10], p[11]);                  \
      u32 w6 = pack2(p[12], p[13]), w7 = pack2(p[14], p[15]);                  \
      asm("v_permlane32_swap_b32 %0, %1" : "+v"(w0), "+v"(w2));                \
      asm("v_permlane32_swap_b32 %0, %1" : "+v"(w1), "+v"(w3));                \
      asm("v_permlane32_swap_b32 %0, %1" : "+v"(w4), "+v"(w6));                \
      asm("v_permlane32_swap_b32 %0, %1" : "+v"(w5), "+v"(w7));                \
      f1.x = w0; f1.y = w1; f1.z = w2; f1.w = w3;                              \
      f2.x = w4; f2.y = w5; f2.z = w6; f2.w = w7;                              \
    }

#define EXPALL(p, s) _Pragma("unroll")                                         \
    for (int r = 0; r < 16; ++r) p[r] = __builtin_amdgcn_exp2f(s[r]);

#define MASKT(p, kv0)                                                          \
    {                                                                          \
      _Pragma("unroll")                                                        \
      for (int r = 0; r < 16; ++r) {                                           \
        const int kvg = (kv0) + (r & 3) + ((r >> 2) << 3) + hi * 4;            \
        if (kvg >= kv_end) p[r] = 0.f;                                         \
      }                                                                        \
    }

#define ATTN_PAIR(P, MASKED, PREFETCH)                                         \
  {                                                                            \
    const int bufA = ((P) & 1) << 1, bufB = bufA + 1;                          \
    _Pragma("unroll")                                                          \
    for (int j = 0; j < 4; ++j) {                                              \
      Vt[bufA][sd0 + j][scc] = vA[j];                                          \
      Vt[bufB][sd0 + j][scc] = vB[j];                                          \
    }                                                                          \
    bf16x4 vAn, vBn; bf16x8 kaAn, kbAn, kaBn, kbBn;                            \
    if (PREFETCH) {                                                            \
      vAn = *(const bf16x4*)vp;                                                \
      vBn = *(const bf16x4*)(vp + 32 * EMB);                                   \
      kaAn = *(const bf16x8*)kp;                                               \
      kbAn = *(const bf16x8*)(kp + 16);                                        \
      kaBn = *(const bf16x8*)(kp + 32 * EMB);                                  \
      kbBn = *(const bf16x8*)(kp + 32 * EMB + 16);                             \
      kp += 64 * EMB; vp += 64 * EMB;                                          \
    }                                                                          \
    f32x16 sAX = {}, sBX = {}, sAY = {}, sBY = {};                             \
    sAX = mfma32(kaA, qfaX, sAX);                                              \
    sBX = mfma32(kaB, qfaX, sBX);                                              \
    sAY = mfma32(kaA, qfaY, sAY);                                              \
    sBY = mfma32(kaB, qfaY, sBY);                                              \
    sAX = mfma32(kbA, qfbX, sAX);                                              \
    sBX = mfma32(kbB, qfbX, sBX);                                              \
    sAY = mfma32(kbA, qfbY, sAY);                                              \
    sBY = mfma32(kbB, qfbY, sBY);                                              \
    float pAX[16], pBX[16], pAY[16], pBY[16];                                  \
    EXPALL(pAX, sAX) EXPALL(pBX, sBX) EXPALL(pAY, sAY) EXPALL(pBY, sBY)        \
    if (MASKED) {                                                              \
      const int kvA = kv_begin + (((P) << 1) << 5);                            \
      const int kvB = kvA + 32;                                                \
      MASKT(pAX, kvA) MASKT(pAY, kvA) MASKT(pBX, kvB) MASKT(pBY, kvB)          \
    }                                                                          \
    u32x4 f1AX, f2AX, f1BX, f2BX, f1AY, f2AY, f1BY, f2BY;                      \
    SOFTPACK(pAX, f1AX, f2AX)                                                  \
    SOFTPACK(pBX, f1BX, f2BX)                                                  \
    SOFTPACK(pAY, f1AY, f2AY)                                                  \
    SOFTPACK(pBY, f1BY, f2BY)                                                  \
    accSX = mfma32(*(bf16x8*)&f1AX, vones, accSX);                             \
    accSX = mfma32(*(bf16x8*)&f2AX, vones, accSX);                             \
    accSX = mfma32(*(bf16x8*)&f1BX, vones, accSX);                             \
    accSX = mfma32(*(bf16x8*)&f2BX, vones, accSX);                             \
    accSY = mfma32(*(bf16x8*)&f1AY, vones, accSY);                             \
    accSY = mfma32(*(bf16x8*)&f2AY, vones, accSY);                             \
    accSY = mfma32(*(bf16x8*)&f1BY, vones, accSY);                             \
    accSY = mfma32(*(bf16x8*)&f2BY, vones, accSY);                             \
    __syncthreads();                                                           \
    const int c1 = ((hi + (q32 >> 3)) & 3) << 3;                               \
    const int c2 = ((2 + hi + (q32 >> 3)) & 3) << 3;                           \
    bf16x8 vf1A = *(const bf16x8*)&Vt[bufA][q32][c1];                          \
    bf16x8 vf2A = *(const bf16x8*)&Vt[bufA][q32][c2];                          \
    bf16x8 vf1B = *(const bf16x8*)&Vt[bufB][q32][c1];                          \
    bf16x8 vf2B = *(const bf16x8*)&Vt[bufB][q32][c2];                          \
    accAX = mfma32(*(bf16x8*)&f1AX, vf1A, accAX);                              \
    accBX = mfma32(*(bf16x8*)&f1BX, vf1B, accBX);                              \
    accAY = mfma32(*(bf16x8*)&f1AY, vf1A, accAY);                              \
    accBY = mfma32(*(bf16x8*)&f1BY, vf1B, accBY);                              \
    accAX = mfma32(*(bf16x8*)&f2AX, vf2A, accAX);                              \
    accBX = mfma32(*(bf16x8*)&f2BX, vf2B, accBX);                              \
    accAY = mfma32(*(bf16x8*)&f2AY, vf2A, accAY);                              \
    accBY = mfma32(*(bf16x8*)&f2BY, vf2B, accBY);                              \
    if (PREFETCH) {                                                            \
      kaA = kaAn; kbA = kbAn; kaB = kaBn; kbB = kbBn;                          \
      vA = vAn; vB = vBn;                                                      \
    }                                                                          \
  }

  #pragma unroll
  for (int P = 0; P < NPAIR - 1; ++P) ATTN_PAIR(P, 0, 1)
  ATTN_PAIR(NPAIR - 1, 1, 0)
#undef ATTN_PAIR
#undef SOFTPACK
#undef EXPALL
#undef MASKT

  bf16_t* Opx = (split == 0) ? Op0 : (split == 1) ? Op1 : Op2;
  const size_t obase = (size_t)bh * SEQ;
  const size_t lbase = ((size_t)split * 16 + bh) * SEQ;
  #pragma unroll
  for (int r = 0; r < 16; ++r) {
    const int qX = qbase + (r & 3) + ((r >> 2) << 3) + hi * 4;
    const int qY = qX + 32;
    if (qX < SEQ) Opx[(obase + qX) * 32 + q32] = (bf16_t)(accAX[r] + accBX[r]);
    if (qY < SEQ) Opx[(obase + qY) * 32 + q32] = (bf16_t)(accAY[r] + accBY[r]);
    // accS columns are all identical (B = ones); lane q32==0 writes Lp
    if (q32 == 0) {
      if (qX < SEQ) Lp[lbase + qX] = accSX[r];
      if (qY < SEQ) Lp[lbase + qY] = accSY[r];
    }
  }
}

// ---------------- merge partials + residual + LayerNorm (temporal) ----------
__global__ __launch_bounds__(256) void merge_kernel(
    const bf16_t* __restrict__ Op0, const bf16_t* __restrict__ Op1,
    const bf16_t* __restrict__ Op2, const float* __restrict__ Lp,
    const bf16_t* __restrict__ resid, const float* __restrict__ gw,
    const float* __restrict__ bw, bf16_t* __restrict__ out)
{
  const int lane = threadIdx.x & 63, wid = threadIdx.x >> 6;
  const int row = blockIdx.x * 4 + wid;        // 0..4999
  const int b = row / SEQ, q = row - b * SEQ;
  const int h = lane >> 3, dl = (lane & 7) * 4;
  const int bh = b * 8 + h;

  const size_t lb = (size_t)bh * SEQ + q;
  const float L = Lp[lb] + Lp[lb + (size_t)16 * SEQ] + Lp[lb + (size_t)32 * SEQ];
  const float invL = 1.f / L;

  const size_t pb = ((size_t)bh * SEQ + q) * 32 + dl;
  bf16x4 o0 = *(const bf16x4*)(Op0 + pb);
  bf16x4 o1 = *(const bf16x4*)(Op1 + pb);
  bf16x4 o2 = *(const bf16x4*)(Op2 + pb);

  const size_t base = (size_t)row * EMB + lane * 4;
  bf16x4 rv = *(const bf16x4*)(resid + base);
  float x[4], s = 0.f, sq = 0.f;
  #pragma unroll
  for (int j = 0; j < 4; ++j) {
    x[j] = ((float)o0[j] + (float)o1[j] + (float)o2[j]) * invL + (float)rv[j];
    s += x[j]; sq += x[j] * x[j];
  }
  #pragma unroll
  for (int m = 1; m < 64; m <<= 1) { s += __shfl_xor(s, m); sq += __shfl_xor(sq, m); }
  const float mean = s * (1.f / EMB);
  const float var = sq * (1.f / EMB) - mean * mean;
  const float rstd = rsqrtf(var + 1e-5f);
  float4 gv = *(const float4*)(gw + lane * 4);
  float4 bv = *(const float4*)(bw + lane * 4);
  bf16x4 ov;
  ov[0] = (__bf16)((x[0] - mean) * rstd * gv.x + bv.x);
  ov[1] = (__bf16)((x[1] - mean) * rstd * gv.y + bv.y);
  ov[2] = (__bf16)((x[2] - mean) * rstd * gv.z + bv.z);
  ov[3] = (__bf16)((x[3] - mean) * rstd * gv.w + bv.w);
  *(bf16x4*)(out + base) = ov;
}

// ---------------- launch ----------------
extern "C" void kernel_launch(void* const* d_in, const int* in_sizes, int n_in,
                              void* d_out, int out_size, void* d_ws, size_t ws_size,
                              hipStream_t stream)
{
  (void)in_sizes; (void)n_in; (void)out_size; (void)ws_size;
  const float* prev  = (const float*)d_in[0];
  const float* query = (const float*)d_in[1];
  const float* img   = (const float*)d_in[2];
  const float* t_wq  = (const float*)d_in[3];
  const float* t_wk  = (const float*)d_in[4];
  const float* t_wv  = (const float*)d_in[5];
  const float* s_wq  = (const float*)d_in[6];
  const float* s_wk  = (const float*)d_in[7];
  const float* s_wv  = (const float*)d_in[8];
  const float* s_wo  = (const float*)d_in[9];
  const float* s_bo  = (const float*)d_in[10];
  const float* n1g = (const float*)d_in[11];
  const float* n1b = (const float*)d_in[12];
  const float* n2g = (const float*)d_in[13];
  const float* n2b = (const float*)d_in[14];
  const float* n3g = (const float*)d_in[15];
  const float* n3b = (const float*)d_in[16];
  const float* ffw1 = (const float*)d_in[17];
  const float* ffb1 = (const float*)d_in[18];
  const float* ffw2 = (const float*)d_in[19];
  const float* ffb2 = (const float*)d_in[20];

  bf16_t* ws   = (bf16_t*)d_ws;
  bf16_t* WT   = ws;                    // weights bf16 transposed
  bf16_t* WTF1 = ws + 458752;
  bf16_t* WTF2 = ws + 589824;
  bf16_t* qbf = ws + 720896;
  bf16_t* pbf = qbf + 1280000;
  bf16_t* ibf = pbf + 1280000;
  bf16_t* qb = ibf + 1280000;
  bf16_t* kb = qb + 1280000;
  bf16_t* vb = kb + 1280000;            // after attn1: reused as x2
  bf16_t* ab = vb + 1280000;            // Op0 (per-split attn partials)
  bf16_t* x1 = ab + 1280000;
  bf16_t* cb = x1 + 1280000;            // Op1
  bf16_t* x2r = cb + 1280000;           // Op2 (old x2 region)
  bf16_t* hb = x2r + 1280000;           // 5000x512; first: spatial K/V
  bf16_t* fb = hb + 2560000;            // OOB-read landing zone (finite)
  float* outp = (float*)d_out;

  bf16_t* Op0 = ab;
  bf16_t* Op1 = cb;
  bf16_t* Op2 = x2r;
  bf16_t* kb2 = hb;                     // spatial K (dead before FFN writes hb)
  bf16_t* vb2 = hb + 1280000;           // spatial V
  bf16_t* X2 = vb;                      // post-attn x2 (vb dead after attn1)
  float*  Lp = (float*)pbf;             // 3*16*2500 floats (pbf dead post-proj5)

  const float log2e = 1.4426950408889634f;
  const float qscT = log2e * (1.f / 16.f);
  const float qscS = log2e * 0.17677669529663687f;

  dim3 blk(256);
  prep_kernel<<<1115, blk, 0, stream>>>(t_wq, t_wk, t_wv, s_wq, s_wk, s_wv,
                                        s_wo, ffw1, ffw2, ws,
                                        query, prev, img, qbf, pbf, ibf);

  dim3 gP5(40, 4, 5), gP1(40, 4), gG512(40, 8);
  // temporal Q/K/V + spatial K/V (spatial K/V only need prep)
  proj5_kernel<<<gP5, blk, 0, stream>>>(qbf, pbf, ibf, WT,
                                        qb, kb, vb, kb2, vb2, qscT);
  attn_part_kernel<<<480, blk, 0, stream>>>(qb, kb, vb, Op0, Op1, Op2, Lp);
  merge_kernel<<<1250, blk, 0, stream>>>(Op0, Op1, Op2, Lp, qbf, n1g, n1b, x1);
  // spatial Q projection
  projq_kernel<<<gP1, blk, 0, stream>>>(x1, WT + 196608, qb, qscS);
  attn_part_kernel<<<480, blk, 0, stream>>>(qb, kb2, vb2, Op0, Op1, Op2, Lp);
  // fused: merge partials + s_wo GEMM + bias + residual(x1) + LN(n2) -> X2
  gemm_ln_merge_kernel<<<313, blk, 0, stream>>>(Op0, Op1, Op2, Lp,
                                                WT + 393216, s_bo, x1,
                                                n2g, n2b, X2, MTOT);
  // FFN
  gemm_relu_kernel<<<gG512, blk, 0, stream>>>(X2, WTF1, ffb1, hb, MTOT, 512);
  gemm_ln_kernel<512><<<313, blk, 0, stream>>>(hb, WTF2, ffb2, X2,
                                               n3g, n3b, nullptr, outp, MTOT);
  (void)fb;
}

// Round 13
// 164.695 us; speedup vs baseline: 1.0388x; 1.0170x over previous
//
#include <hip/hip_runtime.h>
#include <hip/hip_bf16.h>
#include <stdint.h>

// BevFormer block: temporal MHA + LN, spatial cross-MHA(+proj) + LN, FFN + LN.
// I/O f32; internal bf16 MFMA + f32 accum. Flash attention, fixed-max exp2
// softmax, 32x32x16 MFMA, in-register P via permlane32_swap, XCD-pinned group
// swizzle, 2 kv-tiles x 2 q-tiles per iter, mfma32 GEMM bodies, fused GEMM+LN.
// Round 13: exact revert to the round-9 configuration (best measured,
// 165.0 us). Three structural probes on the attn inner loop (merge-fusion
// R10, barrier-free R11, mfma-rowsum R12) were neutral-to-negative; attn is
// latency-plateaued at ~29.5 us/dispatch. This locks in the best state.

typedef __bf16 bf16_t;
typedef __bf16 bf16x8 __attribute__((ext_vector_type(8)));
typedef __bf16 bf16x4 __attribute__((ext_vector_type(4)));
typedef float  f32x4  __attribute__((ext_vector_type(4)));
typedef float  f32x16 __attribute__((ext_vector_type(16)));
typedef uint32_t u32;
typedef uint32_t u32x4 __attribute__((ext_vector_type(4)));

#define NB   2
#define SEQ  2500
#define EMB  256
#define NH   8
#define HD   32
#define MTOT (NB*SEQ)
#define KVSPLIT 3
#define SPLITLEN 834       // splits: [0,834) [834,1668) [1668,2500)
#define NPAIR 14           // 14 pairs = 28 tiles = 896 kv slots (tail masked)

static __device__ __forceinline__ f32x4 mfma16(bf16x8 a, bf16x8 b, f32x4 c) {
  return __builtin_amdgcn_mfma_f32_16x16x32_bf16(a, b, c, 0, 0, 0);
}
static __device__ __forceinline__ f32x16 mfma32(bf16x8 a, bf16x8 b, f32x16 c) {
  return __builtin_amdgcn_mfma_f32_32x32x16_bf16(a, b, c, 0, 0, 0);
}
static __device__ __forceinline__ u32 pack2(float a, float b) {
  union { __bf16 h; unsigned short s; } x, y;
  x.h = (__bf16)a; y.h = (__bf16)b;
  return (u32)x.s | ((u32)y.s << 16);
}

// ---------------- prep: weight transpose->bf16 + activation cvt ----------------
__global__ __launch_bounds__(256) void prep_kernel(
    const float* s0, const float* s1, const float* s2, const float* s3,
    const float* s4, const float* s5, const float* s6, const float* s7,
    const float* s8, bf16_t* wt,
    const float* aq, const float* ap, const float* ai,
    bf16_t* dq, bf16_t* dp, bf16_t* di)
{
  int b = blockIdx.x;
  if (b < 176) {
    const float* src; int R, C, tl; size_t doff;
    if (b < 112) {
      int mi = b >> 4; tl = b & 15; R = 256; C = 256; doff = (size_t)mi * 65536;
      switch (mi) {
        case 0: src = s0; break; case 1: src = s1; break; case 2: src = s2; break;
        case 3: src = s3; break; case 4: src = s4; break; case 5: src = s5; break;
        default: src = s6;
      }
    } else if (b < 144) { tl = b - 112; R = 256; C = 512; doff = 458752; src = s7; }
    else                { tl = b - 144; R = 512; C = 256; doff = 589824; src = s8; }
    const int tpr = C >> 6;
    const int tr = tl / tpr, tc = tl % tpr;
    bf16_t* dst = wt + doff;
    #pragma unroll
    for (int i = 0; i < 16; ++i) {
      int lin = i * 256 + threadIdx.x;
      int lr = lin >> 6, lc = lin & 63;
      int rr = tr * 64 + lr, cc = tc * 64 + lc;
      dst[(size_t)cc * R + rr] = (__bf16)src[(size_t)rr * C + cc];
    }
    return;
  }
  int idx = b - 176;
  int t = idx / 313, r = idx % 313;
  const float* src = (t == 0) ? aq : (t == 1) ? ap : ai;
  bf16_t* dst = (t == 0) ? dq : (t == 1) ? dp : di;
  #pragma unroll
  for (int k = 0; k < 4; ++k) {
    int i = r * 1024 + k * 256 + threadIdx.x;
    if (i < 320000) {
      float4 v = ((const float4*)src)[i];
      bf16x4 o;
      o[0] = (__bf16)v.x; o[1] = (__bf16)v.y; o[2] = (__bf16)v.z; o[3] = (__bf16)v.w;
      ((bf16x4*)dst)[i] = o;
    }
  }
}

// -------- mfma32 GEMM body: wave = 32 rows x 64 cols; block = 4 waves = 128 rows.
template<int K>
static __device__ __forceinline__ void gemm32_body(
    const bf16_t* __restrict__ A, const bf16_t* __restrict__ Wt,
    const float* __restrict__ bias, bf16_t* __restrict__ Cout,
    int M, int N, int relu, float cscale, int bx, int by)
{
  const int tid = threadIdx.x;
  const int lane = tid & 63, wid = tid >> 6;
  const int l31 = lane & 31, hi = lane >> 5;
  const int mbase = bx * 128 + wid * 32;
  const int nbase = by * 64;

  int arow = mbase + l31; if (arow > M - 1) arow = M - 1;
  const bf16_t* ap = A + (size_t)arow * K + hi * 8;
  const bf16_t* bp = Wt + (size_t)(nbase + l31) * K + hi * 8;

  f32x16 acc0 = {}, acc1 = {};
  #pragma unroll
  for (int kk = 0; kk < K; kk += 16) {
    bf16x8 a  = *(const bf16x8*)(ap + kk);
    bf16x8 b0 = *(const bf16x8*)(bp + kk);
    bf16x8 b1 = *(const bf16x8*)(bp + (size_t)32 * K + kk);
    acc0 = mfma32(a, b0, acc0);
    acc1 = mfma32(a, b1, acc1);
  }
  #pragma unroll
  for (int r = 0; r < 16; ++r) {
    const int row = mbase + (r & 3) + ((r >> 2) << 3) + hi * 4;
    if (row < M) {
      const int c0 = nbase + l31;
      const int c1 = nbase + 32 + l31;
      float v0 = acc0[r] * cscale + (bias ? bias[c0] : 0.f);
      float v1 = acc1[r] * cscale + (bias ? bias[c1] : 0.f);
      if (relu) { v0 = fmaxf(v0, 0.f); v1 = fmaxf(v1, 0.f); }
      Cout[(size_t)row * N + c0] = (bf16_t)v0;
      Cout[(size_t)row * N + c1] = (bf16_t)v1;
    }
  }
}

// x2 @ WTF1 (+bias, relu), N=512, K=256
__global__ __launch_bounds__(256) void gemm_relu_kernel(
    const bf16_t* __restrict__ A, const bf16_t* __restrict__ Wt,
    const float* __restrict__ bias, bf16_t* __restrict__ Cout,
    int M, int N)
{
  gemm32_body<256>(A, Wt, bias, Cout, M, N, 1, 1.f, blockIdx.x, blockIdx.y);
}

// three batched projections; qsc applied to C0 (the Q projection)
__global__ __launch_bounds__(256) void proj3_kernel(
    const bf16_t* A0, const bf16_t* W0, bf16_t* C0,
    const bf16_t* A1, const bf16_t* W1, bf16_t* C1,
    const bf16_t* A2, const bf16_t* W2, bf16_t* C2, float qsc)
{
  const bf16_t* A = (blockIdx.z == 0) ? A0 : (blockIdx.z == 1) ? A1 : A2;
  const bf16_t* W = (blockIdx.z == 0) ? W0 : (blockIdx.z == 1) ? W1 : W2;
  bf16_t* C = (blockIdx.z == 0) ? C0 : (blockIdx.z == 1) ? C1 : C2;
  const float cs = (blockIdx.z == 0) ? qsc : 1.f;
  gemm32_body<256>(A, W, nullptr, C, MTOT, 256, 0, cs, blockIdx.x, blockIdx.y);
}

// -------- fused GEMM (N=256) + bias + residual + LayerNorm (mfma16) ---------
template<int K>
__global__ __launch_bounds__(256) void gemm_ln_kernel(
    const bf16_t* __restrict__ A, const bf16_t* __restrict__ Wt,
    const float* __restrict__ bias, const bf16_t* __restrict__ resid,
    const float* __restrict__ gw, const float* __restrict__ bw,
    bf16_t* __restrict__ OutB, float* __restrict__ OutF, int M)
{
  __shared__ float red[16][4][2];
  const int tid = threadIdx.x;
  const int lane = tid & 63, wid = tid >> 6;
  const int l15 = lane & 15, g = lane >> 4;
  const int mbase = blockIdx.x * 16;
  const int nbase = wid * 64;

  int arow = mbase + l15; if (arow > M - 1) arow = M - 1;
  const bf16_t* ap = A + (size_t)arow * K + g * 8;
  const bf16_t* bp = Wt + (size_t)(nbase + l15) * K + g * 8;

  f32x4 acc[4];
  #pragma unroll
  for (int j = 0; j < 4; ++j) acc[j] = (f32x4){0.f,0.f,0.f,0.f};

  #pragma unroll
  for (int kk = 0; kk < K; kk += 32) {
    bf16x8 a = *(const bf16x8*)(ap + kk);
    #pragma unroll
    for (int ct = 0; ct < 4; ++ct) {
      bf16x8 bfr = *(const bf16x8*)(bp + (size_t)ct * 16 * K + kk);
      acc[ct] = mfma16(a, bfr, acc[ct]);
    }
  }

  float x[4][4];
  float xs[4] = {0.f,0.f,0.f,0.f}, xq[4] = {0.f,0.f,0.f,0.f};
  #pragma unroll
  for (int ct = 0; ct < 4; ++ct) {
    const int col = nbase + ct * 16 + l15;
    const float bv = bias[col];
    #pragma unroll
    for (int r = 0; r < 4; ++r) {
      int row = mbase + g * 4 + r; if (row > M - 1) row = M - 1;
      float v = acc[ct][r] + bv + (float)resid[(size_t)row * EMB + col];
      x[ct][r] = v;
      xs[r] += v; xq[r] += v * v;
    }
  }
  #pragma unroll
  for (int r = 0; r < 4; ++r) {
    #pragma unroll
    for (int m = 1; m < 16; m <<= 1) {
      xs[r] += __shfl_xor(xs[r], m);
      xq[r] += __shfl_xor(xq[r], m);
    }
  }
  if (l15 == 0) {
    #pragma unroll
    for (int r = 0; r < 4; ++r) {
      red[g * 4 + r][wid][0] = xs[r];
      red[g * 4 + r][wid][1] = xq[r];
    }
  }
  __syncthreads();
  #pragma unroll
  for (int r = 0; r < 4; ++r) {
    const int rl = g * 4 + r;
    const float S = red[rl][0][0] + red[rl][1][0] + red[rl][2][0] + red[rl][3][0];
    const float Q = red[rl][0][1] + red[rl][1][1] + red[rl][2][1] + red[rl][3][1];
    const float mean = S * (1.f / EMB);
    const float var = Q * (1.f / EMB) - mean * mean;
    const float rstd = rsqrtf(var + 1e-5f);
    const int row = mbase + rl;
    if (row < M) {
      #pragma unroll
      for (int ct = 0; ct < 4; ++ct) {
        const int col = nbase + ct * 16 + l15;
        const float y = (x[ct][r] - mean) * rstd * gw[col] + bw[col];
        if (OutF) OutF[(size_t)row * EMB + col] = y;
        else      OutB[(size_t)row * EMB + col] = (bf16_t)y;
      }
    }
  }
}

// ---------------- flash attention, 32x32x16 MFMA, 2 kv-tiles x 2 q-tiles -----
// grid: 480 blocks = 8 XCD x 60 (bijective swizzle; each XCD owns 2 bh x 3
// splits). block 256 = 4 waves; wave = 64 q rows (two 32-row tiles X/Y).
// 14 kv-pairs per split; last pair masks BOTH tiles against kv_end. OOB K/V
// reads land in adjacent finite workspace; p masked to 0 after exp.
__global__ __launch_bounds__(256, 2) void attn_part_kernel(
    const bf16_t* __restrict__ Qm, const bf16_t* __restrict__ Km,
    const bf16_t* __restrict__ Vm, bf16_t* __restrict__ Op,
    float* __restrict__ Lp)
{
  __shared__ bf16_t Vt[4][32][40];   // V^T, col-rotated: Vt[d][(kv + 8*(d>>3))&31]

  const int tid = threadIdx.x;
  const int lane = tid & 63, wid = tid >> 6;
  const int q32 = lane & 31, hi = lane >> 5;

  // XCD-pinned decode (480 = 8 XCD * 60, bijective)
  const int n = blockIdx.x;
  const int vid = (n & 7) * 60 + (n >> 3);
  const int grp = vid / 10;          // 0..47 = bh*3 + split
  const int sub = vid - grp * 10;    // 0..9 q-block
  const int bh = grp / 3;            // 0..15
  const int split = grp - bh * 3;    // 0..2

  const size_t qoff = (size_t)(bh >> 3) * SEQ * EMB + (bh & 7) * HD;
  const int kv_begin = split * SPLITLEN;
  const int kv_end = min(kv_begin + SPLITLEN, SEQ);

  const int qbase = sub * 256 + wid * 64;
  const int qrX = min(qbase + q32, SEQ - 1);
  const int qrY = min(qbase + 32 + q32, SEQ - 1);
  const bf16x8 qfaX = *(const bf16x8*)(Qm + qoff + (size_t)qrX * EMB + hi * 8);
  const bf16x8 qfbX = *(const bf16x8*)(Qm + qoff + (size_t)qrX * EMB + 16 + hi * 8);
  const bf16x8 qfaY = *(const bf16x8*)(Qm + qoff + (size_t)qrY * EMB + hi * 8);
  const bf16x8 qfbY = *(const bf16x8*)(Qm + qoff + (size_t)qrY * EMB + 16 + hi * 8);

  f32x16 accAX = {}, accBX = {}, accAY = {}, accBY = {};
  float lsumX = 0.f, lsumY = 0.f;

  // V staging map: 256 threads, thread -> (kv, 4 d's)
  const int skv = tid >> 3;           // 0..31
  const int sd0 = (tid & 7) << 2;     // 0..28 step 4
  const int scc = (skv + ((sd0 >> 3) << 3)) & 31;

  // stepped global pointers
  const bf16_t* kp = Km + qoff + (size_t)(kv_begin + q32) * EMB + hi * 8;
  const bf16_t* vp = Vm + qoff + (size_t)(kv_begin + skv) * EMB + sd0;

  // prologue: pair 0 loads (tiles 0,1)
  bf16x4 vA = *(const bf16x4*)vp;
  bf16x4 vB = *(const bf16x4*)(vp + 32 * EMB);
  bf16x8 kaA = *(const bf16x8*)kp;
  bf16x8 kbA = *(const bf16x8*)(kp + 16);
  bf16x8 kaB = *(const bf16x8*)(kp + 32 * EMB);
  bf16x8 kbB = *(const bf16x8*)(kp + 32 * EMB + 16);
  kp += 64 * EMB;
  vp += 64 * EMB;

#define TREE16(dst, p)                                                         \
    {                                                                          \
      float t0 = p[0] + p[1],  t1 = p[2] + p[3];                               \
      float t2 = p[4] + p[5],  t3 = p[6] + p[7];                               \
      float t4 = p[8] + p[9],  t5 = p[10] + p[11];                             \
      float t6 = p[12] + p[13], t7 = p[14] + p[15];                            \
      float u0 = t0 + t1, u1 = t2 + t3, u2 = t4 + t5, u3 = t6 + t7;            \
      dst = (u0 + u1) + (u2 + u3);                                             \
    }

#define SOFTPACK(p, f1, f2)                                                    \
    {                                                                          \
      u32 w0 = pack2(p[0], p[1]),   w1 = pack2(p[2], p[3]);                    \
      u32 w2 = pack2(p[4], p[5]),   w3 = pack2(p[6], p[7]);                    \
      u32 w4 = pack2(p[8], p[9]),   w5 = pack2(p[10], p[11]);                  \
      u32 w6 = pack2(p[12], p[13]), w7 = pack2(p[14], p[15]);                  \
      asm("v_permlane32_swap_b32 %0, %1" : "+v"(w0), "+v"(w2));                \
      asm("v_permlane32_swap_b32 %0, %1" : "+v"(w1), "+v"(w3));                \
      asm("v_permlane32_swap_b32 %0, %1" : "+v"(w4), "+v"(w6));                \
      asm("v_permlane32_swap_b32 %0, %1" : "+v"(w5), "+v"(w7));                \
      f1.x = w0; f1.y = w1; f1.z = w2; f1.w = w3;                              \
      f2.x = w4; f2.y = w5; f2.z = w6; f2.w = w7;                              \
    }

#define EXPALL(p, s) _Pragma("unroll")                                         \
    for (int r = 0; r < 16; ++r) p[r] = __builtin_amdgcn_exp2f(s[r]);

#define MASKT(p, kv0)                                                          \
    {                                                                          \
      _Pragma("unroll")                                                        \
      for (int r = 0; r < 16; ++r) {                                           \
        const int kvg = (kv0) + (r & 3) + ((r >> 2) << 3) + hi * 4;            \
        if (kvg >= kv_end) p[r] = 0.f;                                         \
      }                                                                        \
    }

#define ATTN_PAIR(P, MASKED, PREFETCH)                                         \
  {                                                                            \
    const int bufA = ((P) & 1) << 1, bufB = bufA + 1;                          \
    _Pragma("unroll")                                                          \
    for (int j = 0; j < 4; ++j) {                                              \
      Vt[bufA][sd0 + j][scc] = vA[j];                                          \
      Vt[bufB][sd0 + j][scc] = vB[j];                                          \
    }                                                                          \
    bf16x4 vAn, vBn; bf16x8 kaAn, kbAn, kaBn, kbBn;                            \
    if (PREFETCH) {                                                            \
      vAn = *(const bf16x4*)vp;                                                \
      vBn = *(const bf16x4*)(vp + 32 * EMB);                                   \
      kaAn = *(const bf16x8*)kp;                                               \
      kbAn = *(const bf16x8*)(kp + 16);                                        \
      kaBn = *(const bf16x8*)(kp + 32 * EMB);                                  \
      kbBn = *(const bf16x8*)(kp + 32 * EMB + 16);                             \
      kp += 64 * EMB; vp += 64 * EMB;                                          \
    }                                                                          \
    f32x16 sAX = {}, sBX = {}, sAY = {}, sBY = {};                             \
    sAX = mfma32(kaA, qfaX, sAX);                                              \
    sBX = mfma32(kaB, qfaX, sBX);                                              \
    sAY = mfma32(kaA, qfaY, sAY);                                              \
    sBY = mfma32(kaB, qfaY, sBY);                                              \
    sAX = mfma32(kbA, qfbX, sAX);                                              \
    sBX = mfma32(kbB, qfbX, sBX);                                              \
    sAY = mfma32(kbA, qfbY, sAY);                                              \
    sBY = mfma32(kbB, qfbY, sBY);                                              \
    float pAX[16], pBX[16], pAY[16], pBY[16];                                  \
    EXPALL(pAX, sAX) EXPALL(pBX, sBX) EXPALL(pAY, sAY) EXPALL(pBY, sBY)        \
    if (MASKED) {                                                              \
      const int kvA = kv_begin + (((P) << 1) << 5);                            \
      const int kvB = kvA + 32;                                                \
      MASKT(pAX, kvA) MASKT(pAY, kvA) MASKT(pBX, kvB) MASKT(pBY, kvB)          \
    }                                                                          \
    float ps0, ps1, ps2, ps3;                                                  \
    TREE16(ps0, pAX) TREE16(ps1, pBX) TREE16(ps2, pAY) TREE16(ps3, pBY)        \
    lsumX += ps0 + ps1; lsumY += ps2 + ps3;                                    \
    u32x4 f1AX, f2AX, f1BX, f2BX, f1AY, f2AY, f1BY, f2BY;                      \
    SOFTPACK(pAX, f1AX, f2AX)                                                  \
    SOFTPACK(pBX, f1BX, f2BX)                                                  \
    SOFTPACK(pAY, f1AY, f2AY)                                                  \
    SOFTPACK(pBY, f1BY, f2BY)                                                  \
    __syncthreads();                                                           \
    const int c1 = ((hi + (q32 >> 3)) & 3) << 3;                               \
    const int c2 = ((2 + hi + (q32 >> 3)) & 3) << 3;                           \
    bf16x8 vf1A = *(const bf16x8*)&Vt[bufA][q32][c1];                          \
    bf16x8 vf2A = *(const bf16x8*)&Vt[bufA][q32][c2];                          \
    bf16x8 vf1B = *(const bf16x8*)&Vt[bufB][q32][c1];                          \
    bf16x8 vf2B = *(const bf16x8*)&Vt[bufB][q32][c2];                          \
    accAX = mfma32(*(bf16x8*)&f1AX, vf1A, accAX);                              \
    accBX = mfma32(*(bf16x8*)&f1BX, vf1B, accBX);                              \
    accAY = mfma32(*(bf16x8*)&f1AY, vf1A, accAY);                              \
    accBY = mfma32(*(bf16x8*)&f1BY, vf1B, accBY);                              \
    accAX = mfma32(*(bf16x8*)&f2AX, vf2A, accAX);                              \
    accBX = mfma32(*(bf16x8*)&f2BX, vf2B, accBX);                              \
    accAY = mfma32(*(bf16x8*)&f2AY, vf2A, accAY);                              \
    accBY = mfma32(*(bf16x8*)&f2BY, vf2B, accBY);                              \
    if (PREFETCH) {                                                            \
      kaA = kaAn; kbA = kbAn; kaB = kaBn; kbB = kbBn;                          \
      vA = vAn; vB = vBn;                                                      \
    }                                                                          \
  }

  #pragma unroll
  for (int P = 0; P < NPAIR - 1; ++P) ATTN_PAIR(P, 0, 1)
  ATTN_PAIR(NPAIR - 1, 1, 0)
#undef ATTN_PAIR
#undef SOFTPACK
#undef TREE16
#undef EXPALL
#undef MASKT

  lsumX += __shfl_xor(lsumX, 32);
  lsumY += __shfl_xor(lsumY, 32);
  const size_t pbase = ((size_t)split * 16 + bh) * SEQ;
  #pragma unroll
  for (int r = 0; r < 16; ++r) {
    const int qX = qbase + (r & 3) + ((r >> 2) << 3) + hi * 4;
    const int qY = qX + 32;
    if (qX < SEQ) Op[(pbase + qX) * 32 + q32] = (bf16_t)(accAX[r] + accBX[r]);
    if (qY < SEQ) Op[(pbase + qY) * 32 + q32] = (bf16_t)(accAY[r] + accBY[r]);
  }
  if (lane < 32) {
    const int qX = qbase + lane, qY = qX + 32;
    if (qX < SEQ) Lp[pbase + qX] = lsumX;
    if (qY < SEQ) Lp[pbase + qY] = lsumY;
  }
}

// ---------------- merge partials (+ optional residual + LayerNorm) ----------
__global__ __launch_bounds__(256) void merge_kernel(
    const bf16_t* __restrict__ Op, const float* __restrict__ Lp,
    const bf16_t* __restrict__ resid, const float* __restrict__ gw,
    const float* __restrict__ bw, bf16_t* __restrict__ out, int doLN)
{
  const int lane = threadIdx.x & 63, wid = threadIdx.x >> 6;
  const int row = blockIdx.x * 4 + wid;        // 0..4999
  const int b = row / SEQ, q = row - b * SEQ;
  const int h = lane >> 3, dl = (lane & 7) * 4;
  const int bh = b * 8 + h;

  float L = 0.f;
  float acc[4] = {0.f, 0.f, 0.f, 0.f};
  #pragma unroll
  for (int s = 0; s < KVSPLIT; ++s) {
    const size_t pb = ((size_t)s * 16 + bh) * SEQ + q;
    L += Lp[pb];
    bf16x4 ov = *(const bf16x4*)(Op + pb * 32 + dl);
    #pragma unroll
    for (int j = 0; j < 4; ++j) acc[j] += (float)ov[j];
  }
  const float invL = 1.f / L;
  const size_t base = (size_t)row * EMB + lane * 4;
  if (!doLN) {
    bf16x4 ov;
    #pragma unroll
    for (int j = 0; j < 4; ++j) ov[j] = (__bf16)(acc[j] * invL);
    *(bf16x4*)(out + base) = ov;
    return;
  }
  bf16x4 rv = *(const bf16x4*)(resid + base);
  float x[4], s = 0.f, sq = 0.f;
  #pragma unroll
  for (int j = 0; j < 4; ++j) {
    x[j] = acc[j] * invL + (float)rv[j];
    s += x[j]; sq += x[j] * x[j];
  }
  #pragma unroll
  for (int m = 1; m < 64; m <<= 1) { s += __shfl_xor(s, m); sq += __shfl_xor(sq, m); }
  const float mean = s * (1.f / EMB);
  const float var = sq * (1.f / EMB) - mean * mean;
  const float rstd = rsqrtf(var + 1e-5f);
  float4 gv = *(const float4*)(gw + lane * 4);
  float4 bv = *(const float4*)(bw + lane * 4);
  bf16x4 ov;
  ov[0] = (__bf16)((x[0] - mean) * rstd * gv.x + bv.x);
  ov[1] = (__bf16)((x[1] - mean) * rstd * gv.y + bv.y);
  ov[2] = (__bf16)((x[2] - mean) * rstd * gv.z + bv.z);
  ov[3] = (__bf16)((x[3] - mean) * rstd * gv.w + bv.w);
  *(bf16x4*)(out + base) = ov;
}

// ---------------- launch ----------------
extern "C" void kernel_launch(void* const* d_in, const int* in_sizes, int n_in,
                              void* d_out, int out_size, void* d_ws, size_t ws_size,
                              hipStream_t stream)
{
  (void)in_sizes; (void)n_in; (void)out_size; (void)ws_size;
  const float* prev  = (const float*)d_in[0];
  const float* query = (const float*)d_in[1];
  const float* img   = (const float*)d_in[2];
  const float* t_wq  = (const float*)d_in[3];
  const float* t_wk  = (const float*)d_in[4];
  const float* t_wv  = (const float*)d_in[5];
  const float* s_wq  = (const float*)d_in[6];
  const float* s_wk  = (const float*)d_in[7];
  const float* s_wv  = (const float*)d_in[8];
  const float* s_wo  = (const float*)d_in[9];
  const float* s_bo  = (const float*)d_in[10];
  const float* n1g = (const float*)d_in[11];
  const float* n1b = (const float*)d_in[12];
  const float* n2g = (const float*)d_in[13];
  const float* n2b = (const float*)d_in[14];
  const float* n3g = (const float*)d_in[15];
  const float* n3b = (const float*)d_in[16];
  const float* ffw1 = (const float*)d_in[17];
  const float* ffb1 = (const float*)d_in[18];
  const float* ffw2 = (const float*)d_in[19];
  const float* ffb2 = (const float*)d_in[20];

  bf16_t* ws   = (bf16_t*)d_ws;
  bf16_t* WT   = ws;                    // weights bf16 transposed
  bf16_t* WTF1 = ws + 458752;
  bf16_t* WTF2 = ws + 589824;
  bf16_t* qbf = ws + 720896;
  bf16_t* pbf = qbf + 1280000;
  bf16_t* ibf = pbf + 1280000;
  bf16_t* qb = ibf + 1280000;
  bf16_t* kb = qb + 1280000;
  bf16_t* vb = kb + 1280000;
  bf16_t* ab = vb + 1280000;
  bf16_t* x1 = ab + 1280000;
  bf16_t* cb = x1 + 1280000;
  bf16_t* x2 = cb + 1280000;
  bf16_t* hb = x2 + 1280000;            // 5000x512
  bf16_t* fb = hb + 2560000;
  float* outp = (float*)d_out;
  // attention scratch (regions free during each attention phase):
  bf16_t* Op = cb;                      // 3*16*2500*32 = 3.84M bf16 (cb..)
  float*  Lp = (float*)pbf;             // 3*16*2500 floats = 480KB (prev done)

  const float log2e = 1.4426950408889634f;
  const float qscT = log2e * (1.f / 16.f);
  const float qscS = log2e * 0.17677669529663687f;

  dim3 blk(256);
  prep_kernel<<<1115, blk, 0, stream>>>(t_wq, t_wk, t_wv, s_wq, s_wk, s_wv,
                                        s_wo, ffw1, ffw2, ws,
                                        query, prev, img, qbf, pbf, ibf);

  dim3 gP(40, 4, 3), gG512(40, 8);
  // temporal MHA
  proj3_kernel<<<gP, blk, 0, stream>>>(qbf, WT, qb,
                                       pbf, WT + 65536, kb,
                                       pbf, WT + 131072, vb, qscT);
  attn_part_kernel<<<480, blk, 0, stream>>>(qb, kb, vb, Op, Lp);
  merge_kernel<<<1250, blk, 0, stream>>>(Op, Lp, qbf, n1g, n1b, x1, 1);
  // spatial cross MHA
  proj3_kernel<<<gP, blk, 0, stream>>>(x1,  WT + 196608, qb,
                                       ibf, WT + 262144, kb,
                                       ibf, WT + 327680, vb, qscS);
  attn_part_kernel<<<480, blk, 0, stream>>>(qb, kb, vb, Op, Lp);
  merge_kernel<<<1250, blk, 0, stream>>>(Op, Lp, nullptr, nullptr, nullptr, ab, 0);
  // s_wo projection fused with residual(x1) + LN(n2) -> x2
  gemm_ln_kernel<256><<<313, blk, 0, stream>>>(ab, WT + 393216, s_bo, x1,
                                               n2g, n2b, x2, nullptr, MTOT);
  // FFN
  gemm_relu_kernel<<<gG512, blk, 0, stream>>>(x2, WTF1, ffb1, hb, MTOT, 512);
  gemm_ln_kernel<512><<<313, blk, 0, stream>>>(hb, WTF2, ffb2, x2,
                                               n3g, n3b, nullptr, outp, MTOT);
  (void)fb;
}